// Round 1
// baseline (202.834 us; speedup 1.0000x reference)
//
#include <hip/hip_runtime.h>
#include <hip/hip_bf16.h>

// Problem constants (from reference setup_inputs)
#define B_  16
#define S_  1024
#define D_  300
#define DP  320          // D padded to multiple of 32 (MFMA K-step) with zeros
#define K_  64           // hidden_set_size == compressed dim
#define O_  256          // outputs per batch
#define M_  (B_*S_)      // 16384 rows (b,s)

typedef __attribute__((ext_vector_type(8))) short s8b;   // 8 x bf16 frag (4 VGPRs)
typedef __attribute__((ext_vector_type(4))) float f32x4; // MFMA accumulator

#define MFMA16(a, b, c) __builtin_amdgcn_mfma_f32_16x16x32_bf16((a), (b), (c), 0, 0, 0)

// ---------------------------------------------------------------------------
// Kernel 0: f32 -> bf16 conversion.  Xs -> Xsb [M][DP] (zero-padded cols),
// W -> Wb [64][DP] (zero-padded), hidden_sets -> Hb [O*K][K] (contiguous).
// ---------------------------------------------------------------------------
__global__ __launch_bounds__(256) void k_convert(
        const float* __restrict__ Xs, const float* __restrict__ W,
        const float* __restrict__ H,
        __hip_bfloat16* __restrict__ Xsb, __hip_bfloat16* __restrict__ Wb,
        __hip_bfloat16* __restrict__ Hb) {
    int idx = blockIdx.x * 256 + threadIdx.x;      // grid covers exactly M_*DP
    int r = idx / DP, c = idx - r * DP;
    float v = (c < D_) ? Xs[r * D_ + c] : 0.0f;
    Xsb[idx] = __float2bfloat16(v);
    if (idx < O_ * K_ * K_) {                       // 1,048,576 elements
        Hb[idx] = __float2bfloat16(H[idx]);
    }
    if (idx < K_ * DP) {                            // 20,480 elements
        int k = idx / DP, d = idx - k * DP;
        float wv = (d < D_) ? W[k * D_ + d] : 0.0f;
        Wb[idx] = __float2bfloat16(wv);
    }
}

// ---------------------------------------------------------------------------
// Kernel 1: compress GEMM.  Xc[m][k] = sum_d Xsb[m][d]*Wb[k][d] + bias[k].
// Block = 256 thr (4 waves); block tile 32 rows x 64 cols; per-wave 16x32.
// 512 blocks. K-loop: 10 steps of 32 (DP=320).
// ---------------------------------------------------------------------------
__global__ __launch_bounds__(256) void k_compress(
        const __hip_bfloat16* __restrict__ Xsb,
        const __hip_bfloat16* __restrict__ Wb,
        const float* __restrict__ bias,
        __hip_bfloat16* __restrict__ Xc) {
    int tid  = threadIdx.x;
    int w    = tid >> 6, lane = tid & 63;
    int q    = lane >> 4, r = lane & 15;
    int row0 = blockIdx.x * 32 + (w & 1) * 16;
    int col0 = (w >> 1) * 32;

    f32x4 acc0 = {0.f, 0.f, 0.f, 0.f};
    f32x4 acc1 = {0.f, 0.f, 0.f, 0.f};
    const __hip_bfloat16* arow = Xsb + (size_t)(row0 + r) * DP;
    const __hip_bfloat16* b0row = Wb + (size_t)(col0 + r) * DP;
    const __hip_bfloat16* b1row = Wb + (size_t)(col0 + 16 + r) * DP;

#pragma unroll
    for (int ks = 0; ks < DP / 32; ++ks) {
        int koff = ks * 32 + q * 8;                 // halves; 16B aligned
        s8b a  = __builtin_bit_cast(s8b, *(const uint4*)(arow  + koff));
        s8b b0 = __builtin_bit_cast(s8b, *(const uint4*)(b0row + koff));
        s8b b1 = __builtin_bit_cast(s8b, *(const uint4*)(b1row + koff));
        acc0 = MFMA16(a, b0, acc0);
        acc1 = MFMA16(a, b1, acc1);
    }
    // C/D layout: col = lane&15, row = quad*4 + i
#pragma unroll
    for (int i = 0; i < 4; ++i) {
        int orow = row0 + q * 4 + i;
        int c0   = col0 + r;
        Xc[(size_t)orow * K_ + c0]      = __float2bfloat16(acc0[i] + bias[c0]);
        Xc[(size_t)orow * K_ + c0 + 16] = __float2bfloat16(acc1[i] + bias[c0 + 16]);
    }
}

// ---------------------------------------------------------------------------
// Kernel 2: fused bipartite GEMM + relu + max-over-n + sum-over-s.
// G[bs][o*64+n] = Xc[bs][:] . Hb[o*64+n][:]  (K=64, 2 MFMA k-steps)
// out[b][o] += sum over 128 rows of max(0, max_n G)
// Block = 256 thr (4 waves).  Block tile: 128 rows x 4 o-groups.
// Wave tile: 128 rows x 64 cols (one o).  Grid: 128 row-blocks * 64 = 8192.
// ---------------------------------------------------------------------------
__global__ __launch_bounds__(256) void k_fused(
        const __hip_bfloat16* __restrict__ Xc,
        const __hip_bfloat16* __restrict__ Hb,
        float* __restrict__ out) {
    int tid  = threadIdx.x;
    int w    = tid >> 6, lane = tid & 63;
    int q    = lane >> 4, r = lane & 15;
    int bx   = blockIdx.x;
    int rb   = bx >> 6;          // 0..127 : 128-row block
    int oq   = bx & 63;          // 0..63  : group of 4 o's
    int o    = oq * 4 + w;
    int row0 = rb * 128;
    int batch = rb >> 3;         // 128 rows always within one b (128 | 1024)

    // Preload B fragments: 4 n-tiles x 2 k-halves (Hb rows are k-contiguous)
    s8b bf[4][2];
#pragma unroll
    for (int nt = 0; nt < 4; ++nt) {
        const __hip_bfloat16* hrow = Hb + (size_t)(o * 64 + nt * 16 + r) * 64;
        bf[nt][0] = __builtin_bit_cast(s8b, *(const uint4*)(hrow + q * 8));
        bf[nt][1] = __builtin_bit_cast(s8b, *(const uint4*)(hrow + 32 + q * 8));
    }

    f32x4 acc[8][4];
#pragma unroll
    for (int mt = 0; mt < 8; ++mt)
#pragma unroll
        for (int nt = 0; nt < 4; ++nt)
            acc[mt][nt] = (f32x4){0.f, 0.f, 0.f, 0.f};

#pragma unroll
    for (int mt = 0; mt < 8; ++mt) {
        const __hip_bfloat16* arow = Xc + (size_t)(row0 + mt * 16 + r) * 64;
        s8b a0 = __builtin_bit_cast(s8b, *(const uint4*)(arow + q * 8));
        s8b a1 = __builtin_bit_cast(s8b, *(const uint4*)(arow + 32 + q * 8));
#pragma unroll
        for (int nt = 0; nt < 4; ++nt) {
            acc[mt][nt] = MFMA16(a0, bf[nt][0], acc[mt][nt]);
            acc[mt][nt] = MFMA16(a1, bf[nt][1], acc[mt][nt]);
        }
    }

    // Epilogue: relu+max over the 64 n-columns (4 nt tiles x 16 lane-classes),
    // then sum over this wave's 128 rows, then one atomicAdd per wave.
    float total = 0.0f;
#pragma unroll
    for (int mt = 0; mt < 8; ++mt) {
#pragma unroll
        for (int i = 0; i < 4; ++i) {
            float v = fmaxf(fmaxf(acc[mt][0][i], acc[mt][1][i]),
                            fmaxf(acc[mt][2][i], acc[mt][3][i]));
            v = fmaxf(v, 0.0f);                       // relu folded into max
            v = fmaxf(v, __shfl_xor(v, 1));
            v = fmaxf(v, __shfl_xor(v, 2));
            v = fmaxf(v, __shfl_xor(v, 4));
            v = fmaxf(v, __shfl_xor(v, 8));           // row max, replicated in quad
            total += v;                               // quad q owns rows mt*16+q*4+i
        }
    }
    total += __shfl_xor(total, 16);                   // sum the 4 quads
    total += __shfl_xor(total, 32);
    if (lane == 0) atomicAdd(out + batch * O_ + o, total);
}

// ---------------------------------------------------------------------------
extern "C" void kernel_launch(void* const* d_in, const int* in_sizes, int n_in,
                              void* d_out, int out_size, void* d_ws, size_t ws_size,
                              hipStream_t stream) {
    const float* Xs   = (const float*)d_in[0];   // [16,1024,300]
    const float* W    = (const float*)d_in[1];   // [64,300]
    const float* bias = (const float*)d_in[2];   // [64]
    const float* H    = (const float*)d_in[3];   // [256,64,64]
    float* out = (float*)d_out;                  // [16,256] f32

    char* ws = (char*)d_ws;
    __hip_bfloat16* Xsb = (__hip_bfloat16*)(ws);              // 10,485,760 B
    __hip_bfloat16* Wb  = (__hip_bfloat16*)(ws + 10485760);   //     40,960 B
    __hip_bfloat16* Hb  = (__hip_bfloat16*)(ws + 10526720);   //  2,097,152 B
    __hip_bfloat16* Xc  = (__hip_bfloat16*)(ws + 12623872);   //  2,097,152 B

    hipMemsetAsync(d_out, 0, (size_t)out_size * sizeof(float), stream);
    k_convert <<<(M_ * DP) / 256, 256, 0, stream>>>(Xs, W, H, Xsb, Wb, Hb);
    k_compress<<<M_ / 32,        256, 0, stream>>>(Xsb, Wb, bias, Xc);
    k_fused   <<<(M_ / 128) * (O_ / 4), 256, 0, stream>>>(Xc, Hb, out);
}

// Round 2
// 177.800 us; speedup vs baseline: 1.1408x; 1.1408x over previous
//
#include <hip/hip_runtime.h>
#include <hip/hip_bf16.h>

// Problem constants (from reference setup_inputs)
#define B_  16
#define S_  1024
#define D_  300
#define DP  320          // D padded to multiple of 32 (MFMA K-step) with zeros
#define K_  64           // hidden_set_size == compressed dim
#define O_  256          // outputs per batch
#define M_  (B_*S_)      // 16384 rows (b,s)

typedef __attribute__((ext_vector_type(8))) short s8b;   // 8 x bf16 frag (4 VGPRs)
typedef __attribute__((ext_vector_type(4))) float f32x4; // MFMA accumulator

#define MFMA16(a, b, c) __builtin_amdgcn_mfma_f32_16x16x32_bf16((a), (b), (c), 0, 0, 0)

// ---------------------------------------------------------------------------
// Kernel 0: f32 -> bf16 conversion, one kernel, three blockIdx ranges.
//   blocks [0, 16384)        : Xs rows -> Xsb [M][DP]  (zero-padded cols)
//   blocks [16384, 16448)    : W rows  -> Wb  [64][DP] (zero-padded cols)
//   blocks [16448, 16448+3277): H flat -> Hb  [O*K*K]
// Block = 320 threads (5 waves) = one padded row; no div/mod anywhere.
// ---------------------------------------------------------------------------
#define HBLK 3277   // ceil(1048576 / 320)
__global__ __launch_bounds__(320) void k_convert(
        const float* __restrict__ Xs, const float* __restrict__ W,
        const float* __restrict__ H,
        __hip_bfloat16* __restrict__ Xsb, __hip_bfloat16* __restrict__ Wb,
        __hip_bfloat16* __restrict__ Hb) {
    int bx = blockIdx.x, col = threadIdx.x;
    if (bx < M_) {                                   // Xs rows
        float v = (col < D_) ? Xs[(size_t)bx * D_ + col] : 0.0f;
        Xsb[(size_t)bx * DP + col] = __float2bfloat16(v);
    } else if (bx < M_ + K_) {                       // W rows
        int rw = bx - M_;
        float v = (col < D_) ? W[(size_t)rw * D_ + col] : 0.0f;
        Wb[(size_t)rw * DP + col] = __float2bfloat16(v);
    } else {                                         // H flat
        int i = (bx - M_ - K_) * 320 + col;
        if (i < O_ * K_ * K_) Hb[i] = __float2bfloat16(H[i]);
    }
}

// ---------------------------------------------------------------------------
// Kernel 1: compress GEMM.  Xc[m][k] = sum_d Xsb[m][d]*Wb[k][d] + bias[k].
// Block = 256 thr (4 waves); block tile 16 rows x 64 cols; wave = 16x16 tile.
// 1024 blocks.  K-loop: 10 steps of 32 (DP=320), 1 MFMA each.
// ---------------------------------------------------------------------------
__global__ __launch_bounds__(256) void k_compress(
        const __hip_bfloat16* __restrict__ Xsb,
        const __hip_bfloat16* __restrict__ Wb,
        const float* __restrict__ bias,
        __hip_bfloat16* __restrict__ Xc) {
    int tid  = threadIdx.x;
    int w    = tid >> 6, lane = tid & 63;
    int q    = lane >> 4, r = lane & 15;
    int row0 = blockIdx.x * 16;
    int col0 = w * 16;

    f32x4 acc = {0.f, 0.f, 0.f, 0.f};
    const __hip_bfloat16* arow = Xsb + (size_t)(row0 + r) * DP;
    const __hip_bfloat16* brow = Wb  + (size_t)(col0 + r) * DP;

#pragma unroll
    for (int ks = 0; ks < DP / 32; ++ks) {
        int koff = ks * 32 + q * 8;                 // 16B aligned
        s8b a = __builtin_bit_cast(s8b, *(const uint4*)(arow + koff));
        s8b b = __builtin_bit_cast(s8b, *(const uint4*)(brow + koff));
        acc = MFMA16(a, b, acc);
    }
    // C/D layout: col = lane&15, row = quad*4 + i
#pragma unroll
    for (int i = 0; i < 4; ++i) {
        int orow = row0 + q * 4 + i;
        int c    = col0 + r;
        Xc[(size_t)orow * K_ + c] = __float2bfloat16(acc[i] + bias[c]);
    }
}

// ---------------------------------------------------------------------------
// Kernel 2: fused bipartite GEMM + relu + max-over-n + sum-over-s, TRANSPOSED:
// A = Hb rows (n is the MFMA M-dim), B = Xc rows (bs is the MFMA N-dim), so
// C[row=n][col=bs]: lane holds 4 n-values in regs for ONE bs column
// (col=lane&15, row=quad*4+i).  Max over n = in-lane fmax tree (->v_max3) +
// 2 cross-quad shuffles.  Accumulator is reused per 16-row tile (16 VGPRs,
// not 128) so occupancy recovers.
// Block = 256 thr (4 waves, one o each).  Block tile: 128 bs-rows x 4 o's.
// Grid: 128 row-blocks * 64 o-quads = 8192.
// ---------------------------------------------------------------------------
__global__ __launch_bounds__(256) void k_fused(
        const __hip_bfloat16* __restrict__ Xc,
        const __hip_bfloat16* __restrict__ Hb,
        float* __restrict__ out) {
    int tid   = threadIdx.x;
    int w     = tid >> 6, lane = tid & 63;
    int q     = lane >> 4, r = lane & 15;
    int bx    = blockIdx.x;
    int rb    = bx >> 6;          // 0..127 : 128-row block
    int oq    = bx & 63;          // 0..63  : group of 4 o's
    int o     = oq * 4 + w;
    int row0  = rb * 128;
    int batch = rb >> 3;          // 128 rows always within one b (128 | 1024)

    // Preload A fragments from Hb: this wave's o, 4 n-tiles x 2 k-halves.
    // A-frag layout: m = lane&15 (n within tile), k = quad*8 + j.
    s8b af[4][2];
#pragma unroll
    for (int nt = 0; nt < 4; ++nt) {
        const __hip_bfloat16* hrow = Hb + (size_t)(o * 64 + nt * 16 + r) * 64;
        af[nt][0] = __builtin_bit_cast(s8b, *(const uint4*)(hrow + q * 8));
        af[nt][1] = __builtin_bit_cast(s8b, *(const uint4*)(hrow + 32 + q * 8));
    }

    float total = 0.0f;
#pragma unroll
    for (int mt = 0; mt < 8; ++mt) {
        // B fragment from Xc rows (bs as the N dim): col = lane&15 -> row r
        const __hip_bfloat16* xrow = Xc + (size_t)(row0 + mt * 16 + r) * 64;
        s8b b0 = __builtin_bit_cast(s8b, *(const uint4*)(xrow + q * 8));
        s8b b1 = __builtin_bit_cast(s8b, *(const uint4*)(xrow + 32 + q * 8));

        f32x4 a0 = {0.f,0.f,0.f,0.f}, a1 = {0.f,0.f,0.f,0.f};
        f32x4 a2 = {0.f,0.f,0.f,0.f}, a3 = {0.f,0.f,0.f,0.f};
        a0 = MFMA16(af[0][0], b0, a0);  a0 = MFMA16(af[0][1], b1, a0);
        a1 = MFMA16(af[1][0], b0, a1);  a1 = MFMA16(af[1][1], b1, a1);
        a2 = MFMA16(af[2][0], b0, a2);  a2 = MFMA16(af[2][1], b1, a2);
        a3 = MFMA16(af[3][0], b0, a3);  a3 = MFMA16(af[3][1], b1, a3);

        // In-lane max over the 16 n-values this lane holds (fmax tree ->
        // v_max3), then 2 cross-quad shuffles cover all 64 n.
        float t0 = fmaxf(fmaxf(a0[0], a0[1]), fmaxf(a0[2], a0[3]));
        float t1 = fmaxf(fmaxf(a1[0], a1[1]), fmaxf(a1[2], a1[3]));
        float t2 = fmaxf(fmaxf(a2[0], a2[1]), fmaxf(a2[2], a2[3]));
        float t3 = fmaxf(fmaxf(a3[0], a3[1]), fmaxf(a3[2], a3[3]));
        float v  = fmaxf(fmaxf(t0, t1), fmaxf(t2, t3));
        v = fmaxf(v, __shfl_xor(v, 16));
        v = fmaxf(v, __shfl_xor(v, 32));
        v = fmaxf(v, 0.0f);            // relu folded into the max
        total += v;                     // lane's bs col = row0 + mt*16 + r
    }
    // Sum the 16 bs columns (lanes r=0..15 within each quad-group; totals are
    // quad-replicated, so each group computes the identical full sum).
    total += __shfl_xor(total, 1);
    total += __shfl_xor(total, 2);
    total += __shfl_xor(total, 4);
    total += __shfl_xor(total, 8);
    if (lane == 0) atomicAdd(out + batch * O_ + o, total);
}

// ---------------------------------------------------------------------------
extern "C" void kernel_launch(void* const* d_in, const int* in_sizes, int n_in,
                              void* d_out, int out_size, void* d_ws, size_t ws_size,
                              hipStream_t stream) {
    const float* Xs   = (const float*)d_in[0];   // [16,1024,300]
    const float* W    = (const float*)d_in[1];   // [64,300]
    const float* bias = (const float*)d_in[2];   // [64]
    const float* H    = (const float*)d_in[3];   // [256,64,64]
    float* out = (float*)d_out;                  // [16,256] f32

    char* ws = (char*)d_ws;
    __hip_bfloat16* Xsb = (__hip_bfloat16*)(ws);              // 10,485,760 B
    __hip_bfloat16* Wb  = (__hip_bfloat16*)(ws + 10485760);   //     40,960 B
    __hip_bfloat16* Hb  = (__hip_bfloat16*)(ws + 10526720);   //  2,097,152 B
    __hip_bfloat16* Xc  = (__hip_bfloat16*)(ws + 12623872);   //  2,097,152 B

    hipMemsetAsync(d_out, 0, (size_t)out_size * sizeof(float), stream);
    k_convert <<<M_ + K_ + HBLK, 320, 0, stream>>>(Xs, W, H, Xsb, Wb, Hb);
    k_compress<<<M_ / 16,        256, 0, stream>>>(Xsb, Wb, bias, Xc);
    k_fused   <<<(M_ / 128) * (O_ / 4), 256, 0, stream>>>(Xc, Hb, out);
}

// Round 3
// 125.463 us; speedup vs baseline: 1.6167x; 1.4172x over previous
//
#include <hip/hip_runtime.h>
#include <hip/hip_bf16.h>

// Problem constants (from reference setup_inputs)
#define B_  16
#define S_  1024
#define D_  300
#define DP  320          // D padded to multiple of 32 with zeros
#define K_  64           // hidden_set_size == compressed dim
#define O_  256          // outputs per batch
#define M_  (B_*S_)      // 16384 rows (b,s)

typedef __attribute__((ext_vector_type(8)))  short s8b;    // 8 x bf16 (4 VGPRs)
typedef __attribute__((ext_vector_type(4)))  float f32x4;
typedef __attribute__((ext_vector_type(16))) float f32x16;

#define MFMA16(a,b,c) __builtin_amdgcn_mfma_f32_16x16x32_bf16((a),(b),(c),0,0,0)
#define MFMA32(a,b,c) __builtin_amdgcn_mfma_f32_32x32x16_bf16((a),(b),(c),0,0,0)

__device__ __forceinline__ unsigned short bf16_bits(float f) {
    return __builtin_bit_cast(unsigned short, __float2bfloat16(f));
}

// ---------------------------------------------------------------------------
// Kernel 0: f32 -> bf16 conversion.  8 elements per thread, float4 loads,
// 16B packed stores.  Three blockIdx ranges: Xs (2560 blk), H (512), W (10).
// ---------------------------------------------------------------------------
#define XS_BLK 2560   // 16384*320/8/256
#define H_BLK  512    // 256*64*64/8/256
#define W_BLK  10     // 64*320/8/256
__global__ __launch_bounds__(256) void k_convert(
        const float* __restrict__ Xs, const float* __restrict__ W,
        const float* __restrict__ H,
        __hip_bfloat16* __restrict__ Xsb, __hip_bfloat16* __restrict__ Wb,
        __hip_bfloat16* __restrict__ Hb) {
    int bx = blockIdx.x, t = threadIdx.x;
    const float* src; __hip_bfloat16* dst; int r, c;
    if (bx < XS_BLK) {                       // Xs rows, 40 threads/row
        int g = bx * 256 + t;
        r = g / 40; c = (g - r * 40) * 8;
        src = Xs + (size_t)r * D_; dst = Xsb + (size_t)r * DP + c;
    } else if (bx < XS_BLK + H_BLK) {        // H flat (no padding)
        int g = ((bx - XS_BLK) * 256 + t) * 8;
        float4 f0 = *(const float4*)(H + g);
        float4 f1 = *(const float4*)(H + g + 4);
        union { unsigned short us[8]; uint4 q; } pk;
        pk.us[0]=bf16_bits(f0.x); pk.us[1]=bf16_bits(f0.y);
        pk.us[2]=bf16_bits(f0.z); pk.us[3]=bf16_bits(f0.w);
        pk.us[4]=bf16_bits(f1.x); pk.us[5]=bf16_bits(f1.y);
        pk.us[6]=bf16_bits(f1.z); pk.us[7]=bf16_bits(f1.w);
        *(uint4*)(Hb + g) = pk.q;
        return;
    } else {                                 // W rows, 40 threads/row
        int g = (bx - XS_BLK - H_BLK) * 256 + t;
        r = g / 40; c = (g - r * 40) * 8;
        src = W + (size_t)r * D_; dst = Wb + (size_t)r * DP + c;
    }
    float v[8];
    if (c + 8 <= D_) {                       // fully in-range, 16B aligned
        float4 f0 = *(const float4*)(src + c);
        float4 f1 = *(const float4*)(src + c + 4);
        v[0]=f0.x; v[1]=f0.y; v[2]=f0.z; v[3]=f0.w;
        v[4]=f1.x; v[5]=f1.y; v[6]=f1.z; v[7]=f1.w;
    } else {
#pragma unroll
        for (int j = 0; j < 8; ++j) v[j] = (c + j < D_) ? src[c + j] : 0.0f;
    }
    union { unsigned short us[8]; uint4 q; } pk;
#pragma unroll
    for (int j = 0; j < 8; ++j) pk.us[j] = bf16_bits(v[j]);
    *(uint4*)dst = pk.q;
}

// ---------------------------------------------------------------------------
// Kernel 1: compress GEMM.  Xc[m][k] = sum_d Xsb[m][d]*Wb[k][d] + bias[k].
// Block = 256 thr (4 waves); block tile 16 rows x 64 cols; wave = 16x16.
// K-loop split into 2 independent 5-long MFMA chains for ILP.
// ---------------------------------------------------------------------------
__global__ __launch_bounds__(256) void k_compress(
        const __hip_bfloat16* __restrict__ Xsb,
        const __hip_bfloat16* __restrict__ Wb,
        const float* __restrict__ bias,
        __hip_bfloat16* __restrict__ Xc) {
    int tid  = threadIdx.x;
    int w    = tid >> 6, lane = tid & 63;
    int q    = lane >> 4, r = lane & 15;
    int row0 = blockIdx.x * 16;
    int col0 = w * 16;

    f32x4 acc0 = {0.f,0.f,0.f,0.f}, acc1 = {0.f,0.f,0.f,0.f};
    const __hip_bfloat16* arow = Xsb + (size_t)(row0 + r) * DP;
    const __hip_bfloat16* brow = Wb  + (size_t)(col0 + r) * DP;

#pragma unroll
    for (int ks = 0; ks < 5; ++ks) {
        int k0 = (2 * ks) * 32 + q * 8;
        int k1 = (2 * ks + 1) * 32 + q * 8;
        s8b a0 = __builtin_bit_cast(s8b, *(const uint4*)(arow + k0));
        s8b b0 = __builtin_bit_cast(s8b, *(const uint4*)(brow + k0));
        acc0 = MFMA16(a0, b0, acc0);
        s8b a1 = __builtin_bit_cast(s8b, *(const uint4*)(arow + k1));
        s8b b1 = __builtin_bit_cast(s8b, *(const uint4*)(brow + k1));
        acc1 = MFMA16(a1, b1, acc1);
    }
    // C/D layout: col = lane&15, row = quad*4 + i
#pragma unroll
    for (int i = 0; i < 4; ++i) {
        int orow = row0 + q * 4 + i;
        int c    = col0 + r;
        Xc[(size_t)orow * K_ + c] =
            __float2bfloat16(acc0[i] + acc1[i] + bias[c]);
    }
}

// ---------------------------------------------------------------------------
// Kernel 2: fused bipartite GEMM + relu + max-over-n + sum-over-s.
// 32x32x16 MFMA, transposed: A = Hb (n rows), B = Xc (bs cols), so
// C: col = lane&31 = bs, row = (reg&3)+8*(reg>>2)+4*(lane>>5) = n.
// Block = 256 thr (4 waves, one o each).  Block stages a 256-row Xc slice
// into LDS once (XOR-swizzled 16B chunks), all 4 waves share it.
// Per wave: 8 bs-tiles x (2 n-tiles x 4 k-steps) = 64 MFMA in 2 indep chains.
// Grid: 64 rb x 64 oq = 4096 blocks.
// ---------------------------------------------------------------------------
__global__ __launch_bounds__(256, 4) void k_fused(
        const __hip_bfloat16* __restrict__ Xc,
        const __hip_bfloat16* __restrict__ Hb,
        float* __restrict__ out) {
    __shared__ __hip_bfloat16 lx[256 * 64];   // 32 KB, XOR-swizzled chunks
    int tid   = threadIdx.x;
    int w     = tid >> 6, lane = tid & 63;
    int half  = lane >> 5, l31 = lane & 31;
    int bx    = blockIdx.x;
    int rb    = bx >> 6;          // 0..63 : 256-row slice
    int oq    = bx & 63;          // 0..63 : group of 4 o's
    int o     = oq * 4 + w;
    int row0  = rb * 256;
    int batch = rb >> 2;          // 256 rows always within one b

    // Stage Xc slice: thread t -> row (t>>3)+32i, 16B chunk (t&7).
    // LDS position of chunk c in row r: c ^ (r&7)  (spreads banks on read).
    {
        int r0 = tid >> 3, c = tid & 7;
#pragma unroll
        for (int i = 0; i < 8; ++i) {
            int r = r0 + i * 32;
            uint4 v = *(const uint4*)(Xc + (size_t)(row0 + r) * 64 + c * 8);
            *(uint4*)(&lx[r * 64 + (c ^ (r & 7)) * 8]) = v;
        }
    }

    // Preload A fragments (Hb, this wave's o): 2 n-tiles x 4 k-steps.
    // A layout: row = lane&31, k = (lane>>5)*8 + j.
    s8b af[2][4];
#pragma unroll
    for (int nt = 0; nt < 2; ++nt) {
        const __hip_bfloat16* hrow =
            Hb + (size_t)(o * 64 + nt * 32 + l31) * 64 + half * 8;
#pragma unroll
        for (int ks = 0; ks < 4; ++ks)
            af[nt][ks] = __builtin_bit_cast(s8b, *(const uint4*)(hrow + ks * 16));
    }
    __syncthreads();

    float total = 0.0f;
#pragma unroll
    for (int t = 0; t < 8; ++t) {
        int rr = t * 32 + l31;
        int sw = rr & 7;
        // B layout: col = lane&31 (bs row rr), k = (lane>>5)*8 + j.
        // k-chunk index for step ks is 2*ks+half; un-swizzle with ^sw.
        s8b bf[4];
#pragma unroll
        for (int ks = 0; ks < 4; ++ks)
            bf[ks] = __builtin_bit_cast(s8b,
                *(const uint4*)(&lx[rr * 64 + ((2 * ks + half) ^ sw) * 8]));

        f32x16 a0 = {0.f,0.f,0.f,0.f,0.f,0.f,0.f,0.f,
                     0.f,0.f,0.f,0.f,0.f,0.f,0.f,0.f};
        f32x16 a1 = a0;
#pragma unroll
        for (int ks = 0; ks < 4; ++ks) {
            a0 = MFMA32(af[0][ks], bf[ks], a0);
            a1 = MFMA32(af[1][ks], bf[ks], a1);
        }
        // Max over the 32 n-values this lane holds (balanced tree), then
        // xor-32 merges the complementary half's rows -> max over all 64 n.
        float m0 = fmaxf(fmaxf(a0[0], a0[1]),  fmaxf(a0[2], a0[3]));
        float m1 = fmaxf(fmaxf(a0[4], a0[5]),  fmaxf(a0[6], a0[7]));
        float m2 = fmaxf(fmaxf(a0[8], a0[9]),  fmaxf(a0[10], a0[11]));
        float m3 = fmaxf(fmaxf(a0[12], a0[13]),fmaxf(a0[14], a0[15]));
        float n0 = fmaxf(fmaxf(a1[0], a1[1]),  fmaxf(a1[2], a1[3]));
        float n1 = fmaxf(fmaxf(a1[4], a1[5]),  fmaxf(a1[6], a1[7]));
        float n2 = fmaxf(fmaxf(a1[8], a1[9]),  fmaxf(a1[10], a1[11]));
        float n3 = fmaxf(fmaxf(a1[12], a1[13]),fmaxf(a1[14], a1[15]));
        float v  = fmaxf(fmaxf(fmaxf(m0, m1), fmaxf(m2, m3)),
                         fmaxf(fmaxf(n0, n1), fmaxf(n2, n3)));
        v = fmaxf(v, __shfl_xor(v, 32));
        v = fmaxf(v, 0.0f);                   // relu folded into max
        total += v;                           // lane's bs col = row0+t*32+l31
    }
    // Sum over the 32 bs columns (halves hold identical totals).
    total += __shfl_xor(total, 1);
    total += __shfl_xor(total, 2);
    total += __shfl_xor(total, 4);
    total += __shfl_xor(total, 8);
    total += __shfl_xor(total, 16);
    if (lane == 0) atomicAdd(out + batch * O_ + o, total);
}

// ---------------------------------------------------------------------------
extern "C" void kernel_launch(void* const* d_in, const int* in_sizes, int n_in,
                              void* d_out, int out_size, void* d_ws, size_t ws_size,
                              hipStream_t stream) {
    const float* Xs   = (const float*)d_in[0];   // [16,1024,300]
    const float* W    = (const float*)d_in[1];   // [64,300]
    const float* bias = (const float*)d_in[2];   // [64]
    const float* H    = (const float*)d_in[3];   // [256,64,64]
    float* out = (float*)d_out;                  // [16,256] f32

    char* ws = (char*)d_ws;
    __hip_bfloat16* Xsb = (__hip_bfloat16*)(ws);              // 10,485,760 B
    __hip_bfloat16* Wb  = (__hip_bfloat16*)(ws + 10485760);   //     40,960 B
    __hip_bfloat16* Hb  = (__hip_bfloat16*)(ws + 10526720);   //  2,097,152 B
    __hip_bfloat16* Xc  = (__hip_bfloat16*)(ws + 12623872);   //  2,097,152 B

    hipMemsetAsync(d_out, 0, (size_t)out_size * sizeof(float), stream);
    k_convert <<<XS_BLK + H_BLK + W_BLK, 256, 0, stream>>>(Xs, W, H, Xsb, Wb, Hb);
    k_compress<<<M_ / 16, 256, 0, stream>>>(Xsb, Wb, bias, Xc);
    k_fused   <<<64 * 64, 256, 0, stream>>>(Xc, Hb, out);
}

// Round 4
// 123.884 us; speedup vs baseline: 1.6373x; 1.0127x over previous
//
#include <hip/hip_runtime.h>
#include <hip/hip_bf16.h>

// Problem constants (from reference setup_inputs)
#define B_  16
#define S_  1024
#define D_  300
#define DP  320          // D padded to multiple of 32 with zeros
#define K_  64           // hidden_set_size == compressed dim
#define O_  256          // outputs per batch
#define M_  (B_*S_)      // 16384 rows (b,s)

typedef __attribute__((ext_vector_type(8)))  short s8b;    // 8 x bf16 (4 VGPRs)
typedef __attribute__((ext_vector_type(4)))  float f32x4;
typedef __attribute__((ext_vector_type(16))) float f32x16;

#define MFMA16(a,b,c) __builtin_amdgcn_mfma_f32_16x16x32_bf16((a),(b),(c),0,0,0)
#define MFMA32(a,b,c) __builtin_amdgcn_mfma_f32_32x32x16_bf16((a),(b),(c),0,0,0)

__device__ __forceinline__ unsigned short bf16_bits(float f) {
    return __builtin_bit_cast(unsigned short, __float2bfloat16(f));
}

// ---------------------------------------------------------------------------
// Kernel 0: f32 -> bf16 for W and H only (Xs is consumed as f32 by k_compress).
//   blocks [0, 512)   : H flat -> Hb [O*K*K], 8 el/thread
//   blocks [512, 522) : W rows -> Wb [64][DP] zero-padded, 40 thr/row
// ---------------------------------------------------------------------------
#define H_BLK  512    // 256*64*64/8/256
#define W_BLK  10     // 64*320/8/256
__global__ __launch_bounds__(256) void k_convert(
        const float* __restrict__ W, const float* __restrict__ H,
        __hip_bfloat16* __restrict__ Wb, __hip_bfloat16* __restrict__ Hb) {
    int bx = blockIdx.x, t = threadIdx.x;
    if (bx < H_BLK) {                        // H flat (no padding)
        int g = (bx * 256 + t) * 8;
        float4 f0 = *(const float4*)(H + g);
        float4 f1 = *(const float4*)(H + g + 4);
        union { unsigned short us[8]; uint4 q; } pk;
        pk.us[0]=bf16_bits(f0.x); pk.us[1]=bf16_bits(f0.y);
        pk.us[2]=bf16_bits(f0.z); pk.us[3]=bf16_bits(f0.w);
        pk.us[4]=bf16_bits(f1.x); pk.us[5]=bf16_bits(f1.y);
        pk.us[6]=bf16_bits(f1.z); pk.us[7]=bf16_bits(f1.w);
        *(uint4*)(Hb + g) = pk.q;
        return;
    }
    int g = (bx - H_BLK) * 256 + t;          // W rows, 40 threads/row
    int r = g / 40, c = (g - r * 40) * 8;
    const float* src = W + (size_t)r * D_;
    float v[8];
    if (c + 8 <= D_) {
        float4 f0 = *(const float4*)(src + c);
        float4 f1 = *(const float4*)(src + c + 4);
        v[0]=f0.x; v[1]=f0.y; v[2]=f0.z; v[3]=f0.w;
        v[4]=f1.x; v[5]=f1.y; v[6]=f1.z; v[7]=f1.w;
    } else {
#pragma unroll
        for (int j = 0; j < 8; ++j) v[j] = (c + j < D_) ? src[c + j] : 0.0f;
    }
    union { unsigned short us[8]; uint4 q; } pk;
#pragma unroll
    for (int j = 0; j < 8; ++j) pk.us[j] = bf16_bits(v[j]);
    *(uint4*)(Wb + (size_t)r * DP + c) = pk.q;
}

// ---------------------------------------------------------------------------
// Kernel 1: compress GEMM, A read directly from f32 Xs (convert in regs).
// Xc[m][k] = sum_d Xs[m][d]*Wb[k][d] + bias[k].
// Block = 256 thr (4 waves); block tile 16 rows x 64 cols; wave = 16x16.
// D_=300 is a multiple of 4, so every float4 is fully in- or out-of-range.
// ---------------------------------------------------------------------------
__global__ __launch_bounds__(256) void k_compress(
        const float* __restrict__ Xs,
        const __hip_bfloat16* __restrict__ Wb,
        const float* __restrict__ bias,
        __hip_bfloat16* __restrict__ Xc) {
    int tid  = threadIdx.x;
    int w    = tid >> 6, lane = tid & 63;
    int q    = lane >> 4, r = lane & 15;
    int row0 = blockIdx.x * 16;
    int col0 = w * 16;

    f32x4 acc0 = {0.f,0.f,0.f,0.f}, acc1 = {0.f,0.f,0.f,0.f};
    const float*          arow = Xs + (size_t)(row0 + r) * D_;
    const __hip_bfloat16* brow = Wb + (size_t)(col0 + r) * DP;
    const float4 z4 = {0.f,0.f,0.f,0.f};

#pragma unroll
    for (int ks = 0; ks < 10; ++ks) {
        int k0 = ks * 32 + q * 8;
        float4 f0 = (k0     < D_) ? *(const float4*)(arow + k0)     : z4;
        float4 f1 = (k0 + 4 < D_) ? *(const float4*)(arow + k0 + 4) : z4;
        union { unsigned short us[8]; s8b v; } pk;
        pk.us[0]=bf16_bits(f0.x); pk.us[1]=bf16_bits(f0.y);
        pk.us[2]=bf16_bits(f0.z); pk.us[3]=bf16_bits(f0.w);
        pk.us[4]=bf16_bits(f1.x); pk.us[5]=bf16_bits(f1.y);
        pk.us[6]=bf16_bits(f1.z); pk.us[7]=bf16_bits(f1.w);
        s8b b = __builtin_bit_cast(s8b, *(const uint4*)(brow + k0));
        if (ks & 1) acc1 = MFMA16(pk.v, b, acc1);
        else        acc0 = MFMA16(pk.v, b, acc0);
    }
    // C/D layout: col = lane&15 (out-k), row = quad*4 + i (bs)
#pragma unroll
    for (int i = 0; i < 4; ++i) {
        int orow = row0 + q * 4 + i;
        int c    = col0 + r;
        Xc[(size_t)orow * K_ + c] =
            __float2bfloat16(acc0[i] + acc1[i] + bias[c]);
    }
}

// ---------------------------------------------------------------------------
// Kernel 2: fused bipartite GEMM + relu + max-over-n + sum-over-s.
// One block per (batch, o-quad): loops over 8 slices of 128 bs-rows, staged
// in LDS (XOR-swizzled 16B chunks) with register prefetch of the next slice
// overlapping compute.  32x32x16 MFMA, A = Hb (n rows), B = Xc (bs cols):
// C col = lane&31 = bs, regs+half = n.  Each (batch,o) is owned by exactly
// one wave -> plain store, no atomics, no output memset.
// Grid: 16 batches x 64 o-quads = 1024 blocks = 4 blocks/CU.
// ---------------------------------------------------------------------------
__global__ __launch_bounds__(256, 4) void k_fused(
        const __hip_bfloat16* __restrict__ Xc,
        const __hip_bfloat16* __restrict__ Hb,
        float* __restrict__ out) {
    __shared__ __hip_bfloat16 lx[128 * 64];   // 16 KB
    int tid   = threadIdx.x;
    int w     = tid >> 6, lane = tid & 63;
    int half  = lane >> 5, l31 = lane & 31;
    int bx    = blockIdx.x;
    int batch = bx >> 6;          // 0..15
    int oq    = bx & 63;          // 0..63
    int o     = oq * 4 + w;

    // Preload A fragments (Hb, this wave's o): 2 n-tiles x 4 k-steps.
    // A layout: row = lane&31 (n), k = (lane>>5)*8 + j.
    s8b af[2][4];
#pragma unroll
    for (int nt = 0; nt < 2; ++nt) {
        const __hip_bfloat16* hrow =
            Hb + (size_t)(o * 64 + nt * 32 + l31) * 64 + half * 8;
#pragma unroll
        for (int ks = 0; ks < 4; ++ks)
            af[nt][ks] = __builtin_bit_cast(s8b, *(const uint4*)(hrow + ks * 16));
    }

    // Staging map: thread t -> rows (t>>3)+32i (i=0..3), 16B chunk (t&7).
    // LDS position of chunk c in row r: c ^ (r&7)  (conflict-free reads).
    int sr = tid >> 3, sc = tid & 7;
    const __hip_bfloat16* xbase = Xc + (size_t)batch * S_ * K_;

    // Stage slice 0.
#pragma unroll
    for (int i = 0; i < 4; ++i) {
        int r = sr + i * 32;
        uint4 v = *(const uint4*)(xbase + (size_t)r * 64 + sc * 8);
        *(uint4*)(&lx[r * 64 + (sc ^ (r & 7)) * 8]) = v;
    }

    float total = 0.0f;
    for (int it = 0; it < 8; ++it) {
        __syncthreads();                       // lx holds slice `it`
        uint4 npf[4];
        if (it < 7) {                          // prefetch slice it+1 -> regs
            const __hip_bfloat16* nsrc = xbase + (size_t)(it + 1) * 128 * 64;
#pragma unroll
            for (int i = 0; i < 4; ++i)
                npf[i] = *(const uint4*)(nsrc + (size_t)(sr + i * 32) * 64 + sc * 8);
        }
#pragma unroll
        for (int t = 0; t < 4; ++t) {
            int rr = t * 32 + l31;
            int sw = rr & 7;
            // B layout: col = lane&31 (bs row rr), k = (lane>>5)*8 + j.
            s8b bf[4];
#pragma unroll
            for (int ks = 0; ks < 4; ++ks)
                bf[ks] = __builtin_bit_cast(s8b,
                    *(const uint4*)(&lx[rr * 64 + ((2 * ks + half) ^ sw) * 8]));

            f32x16 a0 = {0.f,0.f,0.f,0.f,0.f,0.f,0.f,0.f,
                         0.f,0.f,0.f,0.f,0.f,0.f,0.f,0.f};
            f32x16 a1 = a0;
#pragma unroll
            for (int ks = 0; ks < 4; ++ks) {
                a0 = MFMA32(af[0][ks], bf[ks], a0);
                a1 = MFMA32(af[1][ks], bf[ks], a1);
            }
            float m0 = fmaxf(fmaxf(a0[0], a0[1]),  fmaxf(a0[2], a0[3]));
            float m1 = fmaxf(fmaxf(a0[4], a0[5]),  fmaxf(a0[6], a0[7]));
            float m2 = fmaxf(fmaxf(a0[8], a0[9]),  fmaxf(a0[10], a0[11]));
            float m3 = fmaxf(fmaxf(a0[12], a0[13]),fmaxf(a0[14], a0[15]));
            float n0 = fmaxf(fmaxf(a1[0], a1[1]),  fmaxf(a1[2], a1[3]));
            float n1 = fmaxf(fmaxf(a1[4], a1[5]),  fmaxf(a1[6], a1[7]));
            float n2 = fmaxf(fmaxf(a1[8], a1[9]),  fmaxf(a1[10], a1[11]));
            float n3 = fmaxf(fmaxf(a1[12], a1[13]),fmaxf(a1[14], a1[15]));
            float v  = fmaxf(fmaxf(fmaxf(m0, m1), fmaxf(m2, m3)),
                             fmaxf(fmaxf(n0, n1), fmaxf(n2, n3)));
            v = fmaxf(v, __shfl_xor(v, 32));   // other half's 32 n-rows
            v = fmaxf(v, 0.0f);                // relu folded into max
            total += v;                        // lane's bs col
        }
        __syncthreads();                       // done reading slice `it`
        if (it < 7) {
#pragma unroll
            for (int i = 0; i < 4; ++i) {
                int r = sr + i * 32;
                *(uint4*)(&lx[r * 64 + (sc ^ (r & 7)) * 8]) = npf[i];
            }
        }
    }
    // Sum over the 32 bs columns (halves hold identical totals).
    total += __shfl_xor(total, 1);
    total += __shfl_xor(total, 2);
    total += __shfl_xor(total, 4);
    total += __shfl_xor(total, 8);
    total += __shfl_xor(total, 16);
    if (lane == 0) out[batch * O_ + o] = total;
}

// ---------------------------------------------------------------------------
extern "C" void kernel_launch(void* const* d_in, const int* in_sizes, int n_in,
                              void* d_out, int out_size, void* d_ws, size_t ws_size,
                              hipStream_t stream) {
    const float* Xs   = (const float*)d_in[0];   // [16,1024,300]
    const float* W    = (const float*)d_in[1];   // [64,300]
    const float* bias = (const float*)d_in[2];   // [64]
    const float* H    = (const float*)d_in[3];   // [256,64,64]
    float* out = (float*)d_out;                  // [16,256] f32

    char* ws = (char*)d_ws;
    __hip_bfloat16* Wb = (__hip_bfloat16*)(ws);               //     40,960 B
    __hip_bfloat16* Hb = (__hip_bfloat16*)(ws + 40960);       //  2,097,152 B
    __hip_bfloat16* Xc = (__hip_bfloat16*)(ws + 2138112);     //  2,097,152 B

    k_convert <<<H_BLK + W_BLK, 256, 0, stream>>>(W, H, Wb, Hb);
    k_compress<<<M_ / 16, 256, 0, stream>>>(Xs, Wb, bias, Xc);
    k_fused   <<<B_ * (O_ / 4), 256, 0, stream>>>(Xc, Hb, out);
}